// Round 3
// baseline (325.821 us; speedup 1.0000x reference)
//
#include <hip/hip_runtime.h>
#include <cstdint>

#define BATCH 512
#define CIN   64
#define HH    32
#define WW    64
#define HW    2048
#define C1    32
#define C2    16
#define C3    8
#define C4    4
#define NOUT  256
#define KFC   8192
#define NODES 128
#define KS    32                      // FC K-split
#define GF_SIZE (BATCH * NODES * CIN)

typedef __attribute__((ext_vector_type(8))) short bfrag;   // 8 bf16 (4 VGPRs)
typedef __attribute__((ext_vector_type(4))) float ffrag;   // 4 fp32 acc

__device__ __forceinline__ ushort bf_trunc(float f) { return (ushort)(__float_as_uint(f) >> 16); }
__device__ __forceinline__ float  bf_truncf(float f) { return __uint_as_float(__float_as_uint(f) & 0xffff0000u); }
__device__ __forceinline__ ushort f2bf(float f) {
  uint32_t u = __float_as_uint(f);
  return (ushort)((u + 0x7fffu + ((u >> 16) & 1u)) >> 16);
}
__device__ __forceinline__ uint32_t pack2(float a, float b) {
  return (uint32_t)f2bf(a) | ((uint32_t)f2bf(b) << 16);
}
__device__ __forceinline__ uint32_t packhi2(float a, float b) {
  return (uint32_t)bf_trunc(a) | ((uint32_t)bf_trunc(b) << 16);
}

// ---------------------------------------------------------------------------
// K1: conv1 (1x1, 64->32) + conv2 (3x3 pad1, 32->16) fused, MFMA bf16,
// split-precision (fp32-grade). 16-row tiles, 512 threads (8 waves),
// LDS = h1 only: [18 rows][66 cols(pad)][32ch bf16] = 76032 B -> 2 blk/CU
// = 4 waves/SIMD. W1/W2 fragments built from global (L1-resident).
// x NCHW fp32 -> h2 NHWC fp32 [cb][32][64][16].  grid (2, cb).
// ---------------------------------------------------------------------------
__global__ __launch_bounds__(512, 4) void k_conv12(
    const float* __restrict__ x, const float* __restrict__ w11, const float* __restrict__ b11,
    const float* __restrict__ w12, const float* __restrict__ b12,
    float* __restrict__ h2, int b0)
{
  __shared__ __align__(16) char h1s[18 * 66 * 64];   // 76032 B
  const int tid = threadIdx.x;
  const int l   = tid & 63;
  const int wv  = tid >> 6;    // 0..7
  const int lr  = l & 15;
  const int lg  = l >> 4;
  const int r0  = blockIdx.x * 16;
  const int bg  = b0 + blockIdx.y;
  const float* xb = x + (size_t)bg * CIN * HW;

  // zero the padded columns (colb = 0 and 65) of all 18 rows
  if (tid < 288) {
    int cell = tid >> 3, q = tid & 7;
    int row = cell >> 1, colb = (cell & 1) ? 65 : 0;
    *(uint2*)(h1s + ((row * 66 + colb) << 6) + q * 8) = uint2{0u, 0u};
  }

  // W1 fragments from global
  bfrag w1h[2][2], w1l[2][2];   // [Mtile][kstep]
  #pragma unroll
  for (int m = 0; m < 2; ++m) {
    #pragma unroll
    for (int ks = 0; ks < 2; ++ks) {
      const float* wp = w11 + (m * 16 + lr) * 64 + ks * 32 + lg * 8;
      #pragma unroll
      for (int e = 0; e < 8; ++e) {
        float v = wp[e];
        w1h[m][ks][e] = (short)bf_trunc(v);
        w1l[m][ks][e] = (short)f2bf(v - bf_truncf(v));
      }
    }
  }
  float bias1[2][4];
  #pragma unroll
  for (int m = 0; m < 2; ++m) {
    #pragma unroll
    for (int r = 0; r < 4; ++r) bias1[m][r] = b11[m * 16 + lg * 4 + r];
  }

  // ---- Phase A: conv1 -> h1 LDS. 72 tiles (18 rows x 4 col-tiles), 9/wave.
  #pragma unroll 1
  for (int i = 0; i < 9; ++i) {
    const int nt   = wv * 9 + i;
    const int ry   = nt >> 2;             // 0..17
    const int col0 = (nt & 3) << 4;
    const int y    = r0 - 1 + ry;
    const int colb = col0 + 1 + lr;
    if (y >= 0 && y < HH) {
      float xv[16];
      const float* xp = xb + y * WW + col0 + lr;
      #pragma unroll
      for (int ks = 0; ks < 2; ++ks) {
        #pragma unroll
        for (int e = 0; e < 8; ++e)
          xv[ks * 8 + e] = xp[(ks * 32 + lg * 8 + e) * HW];
      }
      bfrag xh[2], xl[2];
      #pragma unroll
      for (int ks = 0; ks < 2; ++ks) {
        #pragma unroll
        for (int e = 0; e < 8; ++e) {
          float v = xv[ks * 8 + e];
          xh[ks][e] = (short)bf_trunc(v);
          xl[ks][e] = (short)f2bf(v - bf_truncf(v));
        }
      }
      ffrag a0 = {0.f, 0.f, 0.f, 0.f}, a1 = {0.f, 0.f, 0.f, 0.f};
      #pragma unroll
      for (int ks = 0; ks < 2; ++ks) {
        a0 = __builtin_amdgcn_mfma_f32_16x16x32_bf16(w1h[0][ks], xh[ks], a0, 0, 0, 0);
        a0 = __builtin_amdgcn_mfma_f32_16x16x32_bf16(w1h[0][ks], xl[ks], a0, 0, 0, 0);
        a0 = __builtin_amdgcn_mfma_f32_16x16x32_bf16(w1l[0][ks], xh[ks], a0, 0, 0, 0);
        a1 = __builtin_amdgcn_mfma_f32_16x16x32_bf16(w1h[1][ks], xh[ks], a1, 0, 0, 0);
        a1 = __builtin_amdgcn_mfma_f32_16x16x32_bf16(w1h[1][ks], xl[ks], a1, 0, 0, 0);
        a1 = __builtin_amdgcn_mfma_f32_16x16x32_bf16(w1l[1][ks], xh[ks], a1, 0, 0, 0);
      }
      #pragma unroll
      for (int m = 0; m < 2; ++m) {
        float v0 = fmaxf((m ? a1[0] : a0[0]) + bias1[m][0], 0.f);
        float v1 = fmaxf((m ? a1[1] : a0[1]) + bias1[m][1], 0.f);
        float v2 = fmaxf((m ? a1[2] : a0[2]) + bias1[m][2], 0.f);
        float v3 = fmaxf((m ? a1[3] : a0[3]) + bias1[m][3], 0.f);
        int chunk = (m * 2 + (lg >> 1)) ^ ((colb >> 1) & 3);
        char* dst = h1s + ((ry * 66 + colb) << 6) + (chunk << 4) + (lg & 1) * 8;
        *(uint2*)dst = uint2{pack2(v0, v1), pack2(v2, v3)};
      }
    } else {
      #pragma unroll
      for (int m = 0; m < 2; ++m) {
        int chunk = (m * 2 + (lg >> 1)) ^ ((colb >> 1) & 3);
        char* dst = h1s + ((ry * 66 + colb) << 6) + (chunk << 4) + (lg & 1) * 8;
        *(uint2*)dst = uint2{0u, 0u};
      }
    }
  }

  // W2 fragments from global (w12 is 18 KB, L1-resident after first wave)
  bfrag w2h[9], w2l[9];
  #pragma unroll
  for (int t = 0; t < 9; ++t) {
    const float* wp = w12 + lr * 288 + t;
    #pragma unroll
    for (int e = 0; e < 8; ++e) {
      float v = wp[(lg * 8 + e) * 9];
      w2h[t][e] = (short)bf_trunc(v);
      w2l[t][e] = (short)f2bf(v - bf_truncf(v));
    }
  }
  float bias2[4];
  #pragma unroll
  for (int r = 0; r < 4; ++r) bias2[r] = b12[lg * 4 + r];
  __syncthreads();

  // ---- Phase B: conv2 (9 taps, K=32). 64 tiles (16 rows x 4), 8/wave.
  #pragma unroll 1
  for (int i = 0; i < 8; ++i) {
    const int nt   = wv * 8 + i;
    const int ryo  = nt >> 2;             // 0..15
    const int col0 = (nt & 3) << 4;
    ffrag acc = {0.f, 0.f, 0.f, 0.f};
    #pragma unroll
    for (int ky = 0; ky < 3; ++ky) {
      const int row = ryo + ky;
      #pragma unroll
      for (int kx = 0; kx < 3; ++kx) {
        const int colb  = col0 + lr + kx;
        const int chunk = lg ^ ((colb >> 1) & 3);
        const bfrag hv = *(const bfrag*)(h1s + ((row * 66 + colb) << 6) + (chunk << 4));
        acc = __builtin_amdgcn_mfma_f32_16x16x32_bf16(w2h[ky * 3 + kx], hv, acc, 0, 0, 0);
        acc = __builtin_amdgcn_mfma_f32_16x16x32_bf16(w2l[ky * 3 + kx], hv, acc, 0, 0, 0);
      }
    }
    const int px = (r0 + ryo) * WW + col0 + lr;
    float4 o;
    o.x = fmaxf(acc[0] + bias2[0], 0.f);
    o.y = fmaxf(acc[1] + bias2[1], 0.f);
    o.z = fmaxf(acc[2] + bias2[2], 0.f);
    o.w = fmaxf(acc[3] + bias2[3], 0.f);
    *(float4*)(h2 + ((size_t)blockIdx.y * HW + px) * 16 + lg * 4) = o;
  }
}

// ---------------------------------------------------------------------------
// K2: conv3 (1x1, 16->8, relu) + conv4 (3x3 pad1, 8->4, relu), fused (VALU).
// h2 NHWC fp32 -> h4 bf16 hi/lo planes [cb][8192] (FC flatten order).
// ---------------------------------------------------------------------------
__global__ __launch_bounds__(256) void k_conv34(
    const float* __restrict__ h2, const float* __restrict__ w21, const float* __restrict__ b21,
    const float* __restrict__ w22, const float* __restrict__ b22,
    ushort* __restrict__ h4h, ushort* __restrict__ h4l)
{
  __shared__ float h3s[18][64][9];
  __shared__ float __align__(16) w21s[128];
  __shared__ float __align__(16) w22s[288];
  const int tid = threadIdx.x;
  const int r0  = blockIdx.x * 16;
  const size_t b = blockIdx.y;

  for (int i = tid; i < 128; i += 256) w21s[(i & 15) * 8 + (i >> 4)] = w21[i];
  for (int i = tid; i < 288; i += 256) {
    int o = i / 72, r = i - o * 72, c = r / 9, tap = r - c * 9;
    w22s[(tap * 8 + c) * 4 + o] = w22[i];
  }
  __syncthreads();

  for (int p = tid; p < 18 * 64; p += 256) {
    const int ry = p >> 6, wc = p & 63;
    const int y  = r0 - 1 + ry;
    float* hd = &h3s[ry][wc][0];
    if (y >= 0 && y < HH) {
      const float4* hp = (const float4*)(h2 + ((b * HH + y) * WW + wc) * C2);
      float4 v0 = hp[0], v1 = hp[1], v2 = hp[2], v3 = hp[3];
      float xv[16] = {v0.x, v0.y, v0.z, v0.w, v1.x, v1.y, v1.z, v1.w,
                      v2.x, v2.y, v2.z, v2.w, v3.x, v3.y, v3.z, v3.w};
      float acc[C3];
      #pragma unroll
      for (int o = 0; o < C3; ++o) acc[o] = b21[o];
      #pragma unroll
      for (int c = 0; c < 16; ++c) {
        const float4* wr = (const float4*)&w21s[c * 8];
        float4 a = wr[0], d = wr[1];
        float v = xv[c];
        acc[0] = fmaf(v, a.x, acc[0]); acc[1] = fmaf(v, a.y, acc[1]);
        acc[2] = fmaf(v, a.z, acc[2]); acc[3] = fmaf(v, a.w, acc[3]);
        acc[4] = fmaf(v, d.x, acc[4]); acc[5] = fmaf(v, d.y, acc[5]);
        acc[6] = fmaf(v, d.z, acc[6]); acc[7] = fmaf(v, d.w, acc[7]);
      }
      #pragma unroll
      for (int c = 0; c < C3; ++c) hd[c] = fmaxf(acc[c], 0.f);
    } else {
      #pragma unroll
      for (int c = 0; c < C3; ++c) hd[c] = 0.f;
    }
  }
  __syncthreads();

  for (int p = tid; p < 1024; p += 256) {
    const int yl = p >> 6, wc = p & 63, ry = yl + 1;
    float acc[C4] = {b22[0], b22[1], b22[2], b22[3]};
    #pragma unroll
    for (int ky = 0; ky < 3; ++ky) {
      #pragma unroll
      for (int kx = 0; kx < 3; ++kx) {
        const int wcc = wc + kx - 1;
        if (wcc < 0 || wcc >= WW) continue;
        const float* hb = &h3s[ry + ky - 1][wcc][0];
        const int tap = ky * 3 + kx;
        #pragma unroll
        for (int c = 0; c < C3; ++c) {
          float v = hb[c];
          float4 w4 = *(const float4*)&w22s[(tap * 8 + c) * 4];
          acc[0] = fmaf(v, w4.x, acc[0]); acc[1] = fmaf(v, w4.y, acc[1]);
          acc[2] = fmaf(v, w4.z, acc[2]); acc[3] = fmaf(v, w4.w, acc[3]);
        }
      }
    }
    const size_t base = b * KFC + (r0 + yl) * WW + wc;
    #pragma unroll
    for (int o = 0; o < C4; ++o) {
      float v = fmaxf(acc[o], 0.f);
      h4h[base + (size_t)o * HW] = bf_trunc(v);
      h4l[base + (size_t)o * HW] = f2bf(v - bf_truncf(v));
    }
  }
}

// ---------------------------------------------------------------------------
// K2b: fcw fp32 -> bf16 hi/lo planes (once per launch, deterministic)
// ---------------------------------------------------------------------------
__global__ __launch_bounds__(256) void k_cvt_fcw(
    const float* __restrict__ w, ushort* __restrict__ hi, ushort* __restrict__ lo)
{
  const int i = (blockIdx.x * 256 + threadIdx.x) * 8;
  const float4 a = *(const float4*)(w + i);
  const float4 b = *(const float4*)(w + i + 4);
  uint4 hv, lv;
  hv.x = packhi2(a.x, a.y); hv.y = packhi2(a.z, a.w);
  hv.z = packhi2(b.x, b.y); hv.w = packhi2(b.z, b.w);
  lv.x = pack2(a.x - bf_truncf(a.x), a.y - bf_truncf(a.y));
  lv.y = pack2(a.z - bf_truncf(a.z), a.w - bf_truncf(a.w));
  lv.z = pack2(b.x - bf_truncf(b.x), b.y - bf_truncf(b.y));
  lv.w = pack2(b.z - bf_truncf(b.z), b.w - bf_truncf(b.w));
  *(uint4*)(hi + i) = hv;
  *(uint4*)(lo + i) = lv;
}

// ---------------------------------------------------------------------------
// K3: FC GEMM, MFMA bf16 3-product (hi/lo), K split KS-way, deterministic.
// A = h4 [cb][8192] (hi/lo), B = fcw [256][8192] (hi/lo).
// grid (ceil(cb/64), 4, KS), block 256 (4 waves; wave = 32M x 32N).
// ---------------------------------------------------------------------------
__global__ __launch_bounds__(256) void k_fc(
    const ushort* __restrict__ Ahp, const ushort* __restrict__ Alp,
    const ushort* __restrict__ Bhp, const ushort* __restrict__ Blp,
    float* __restrict__ zpart, int cb)
{
  const int tid = threadIdx.x;
  const int l   = tid & 63;
  const int wv  = tid >> 6;
  const int lr  = l & 15;
  const int lg  = l >> 4;
  const int m0  = blockIdx.x * 64 + (wv >> 1) * 32;
  const int n0  = blockIdx.y * 64 + (wv & 1) * 32;
  const int k0  = blockIdx.z * (KFC / KS);     // 256 per split

  int mrow[2], nrow[2];
  #pragma unroll
  for (int t = 0; t < 2; ++t) {
    int m = m0 + t * 16 + lr;
    mrow[t] = m < cb ? m : cb - 1;             // clamp; masked at write
    nrow[t] = n0 + t * 16 + lr;
  }
  ffrag acc[2][2] = {};

  #pragma unroll 1
  for (int kc = 0; kc < (KFC / KS) / 32; ++kc) {
    const int k = k0 + kc * 32 + lg * 8;
    bfrag ah[2], al[2], bh[2], bl[2];
    #pragma unroll
    for (int t = 0; t < 2; ++t) {
      ah[t] = *(const bfrag*)(Ahp + (size_t)mrow[t] * KFC + k);
      al[t] = *(const bfrag*)(Alp + (size_t)mrow[t] * KFC + k);
      bh[t] = *(const bfrag*)(Bhp + (size_t)nrow[t] * KFC + k);
      bl[t] = *(const bfrag*)(Blp + (size_t)nrow[t] * KFC + k);
    }
    #pragma unroll
    for (int mt = 0; mt < 2; ++mt) {
      #pragma unroll
      for (int nt = 0; nt < 2; ++nt) {
        acc[mt][nt] = __builtin_amdgcn_mfma_f32_16x16x32_bf16(ah[mt], bh[nt], acc[mt][nt], 0, 0, 0);
        acc[mt][nt] = __builtin_amdgcn_mfma_f32_16x16x32_bf16(ah[mt], bl[nt], acc[mt][nt], 0, 0, 0);
        acc[mt][nt] = __builtin_amdgcn_mfma_f32_16x16x32_bf16(al[mt], bh[nt], acc[mt][nt], 0, 0, 0);
      }
    }
  }

  #pragma unroll
  for (int mt = 0; mt < 2; ++mt) {
    #pragma unroll
    for (int r = 0; r < 4; ++r) {
      const int m = m0 + mt * 16 + lg * 4 + r;
      if (m < cb) {
        #pragma unroll
        for (int nt = 0; nt < 2; ++nt)
          zpart[((size_t)blockIdx.z * cb + m) * NOUT + n0 + nt * 16 + lr] = acc[mt][nt][r];
      }
    }
  }
}

// ---------------------------------------------------------------------------
// K4: reduce partials + bias -> sigmoid(3z) -> coord
// ---------------------------------------------------------------------------
__global__ __launch_bounds__(256) void k_coord(
    const float* __restrict__ zpart, const float* __restrict__ fcb,
    float* __restrict__ out, int cb, int b0)
{
  const int b = blockIdx.x;
  const int o = threadIdx.x;
  float z = fcb[o];
  #pragma unroll 8
  for (int kb = 0; kb < KS; ++kb) z += zpart[((size_t)kb * cb + b) * NOUT + o];
  float s = 1.f / (1.f + __expf(-3.f * z));
  const int node = o >> 1, comp = o & 1;
  out[GF_SIZE + (((size_t)(b0 + b) * NODES + node) << 1) + comp] = s * (comp ? 63.f : 31.f);
}

// ---------------------------------------------------------------------------
// K5: bilinear gather. One 64-lane group per (b,node); lane = channel.
// ---------------------------------------------------------------------------
__global__ __launch_bounds__(256) void k_gather(
    const float* __restrict__ x, float* __restrict__ out, int b0)
{
  const int pair = blockIdx.x * 4 + (threadIdx.x >> 6);
  const int c    = threadIdx.x & 63;
  const int bl   = pair >> 7;
  const int node = pair & 127;
  const int bg   = b0 + bl;
  const float* cp = out + GF_SIZE + ((size_t)bg * NODES + node) * 2;
  float chv = fminf(fmaxf(cp[0], 0.f), 31.f);
  float cwv = fminf(fmaxf(cp[1], 0.f), 63.f);
  float fh = floorf(chv), fw = floorf(cwv);
  int h0 = (int)fh, h1i = (int)ceilf(chv);
  int w0 = (int)fw, w1i = (int)ceilf(cwv);
  float oh = chv - fh, ow = cwv - fw;
  const float* xb = x + ((size_t)bg * CIN + c) * HW;
  float v_lt = xb[h0 * WW + w0];
  float v_rt = xb[h1i * WW + w0];
  float v_lb = xb[h0 * WW + w1i];
  float v_rb = xb[h1i * WW + w1i];
  float vt = v_lt + oh * (v_rt - v_lt);
  float vb = v_lb + oh * (v_rb - v_lb);
  out[((size_t)bg * NODES + node) * CIN + c] = vt + ow * (vb - vt);
}

// ---------------------------------------------------------------------------
extern "C" void kernel_launch(void* const* d_in, const int* in_sizes, int n_in,
                              void* d_out, int out_size, void* d_ws, size_t ws_size,
                              hipStream_t stream)
{
  (void)in_sizes; (void)n_in; (void)out_size;
  const float* x   = (const float*)d_in[0];
  const float* w11 = (const float*)d_in[1];
  const float* b11 = (const float*)d_in[2];
  const float* w12 = (const float*)d_in[3];
  const float* b12 = (const float*)d_in[4];
  const float* w21 = (const float*)d_in[5];
  const float* b21 = (const float*)d_in[6];
  const float* w22 = (const float*)d_in[7];
  const float* b22 = (const float*)d_in[8];
  const float* fcw = (const float*)d_in[9];
  const float* fcb = (const float*)d_in[10];
  float* out = (float*)d_out;
  char* wsb  = (char*)d_ws;

  // per-b: h2 fp32 (131072) + h4 hi/lo bf16 (2x16384) + zpart (KS*256*4 = 32768)
  const size_t perB  = 131072 + 16384 + 16384 + (size_t)KS * NOUT * 4;
  const size_t fixed = 2 * 4194304;            // fcw hi/lo planes
  size_t avail = ws_size > fixed ? ws_size - fixed : perB;
  size_t cbmax = avail / perB;
  int CB = (int)(cbmax < (size_t)BATCH ? cbmax : (size_t)BATCH);
  if (CB < 1) CB = 1;

  char* p = wsb;
  float*  h2v  = (float*)p;   p += (size_t)CB * 131072;
  ushort* h4h  = (ushort*)p;  p += (size_t)CB * 16384;
  ushort* h4l  = (ushort*)p;  p += (size_t)CB * 16384;
  float*  zpv  = (float*)p;   p += (size_t)CB * KS * NOUT * 4;
  ushort* fcwh = (ushort*)p;  p += 4194304;
  ushort* fcwl = (ushort*)p;

  k_cvt_fcw<<<dim3(NOUT * KFC / (256 * 8)), 256, 0, stream>>>(fcw, fcwh, fcwl);

  for (int b0 = 0; b0 < BATCH; b0 += CB) {
    const int cb = (BATCH - b0 < CB) ? (BATCH - b0) : CB;
    k_conv12<<<dim3(2, cb), 512, 0, stream>>>(x, w11, b11, w12, b12, h2v, b0);
    k_conv34<<<dim3(2, cb), 256, 0, stream>>>(h2v, w21, b21, w22, b22, h4h, h4l);
    k_fc<<<dim3((cb + 63) / 64, 4, KS), 256, 0, stream>>>(h4h, h4l, fcwh, fcwl, zpv, cb);
    k_coord<<<dim3(cb), 256, 0, stream>>>(zpv, fcb, out, cb, b0);
    k_gather<<<dim3(cb * 32), 256, 0, stream>>>(x, out, b0);
  }
}

// Round 4
// 253.978 us; speedup vs baseline: 1.2829x; 1.2829x over previous
//
#include <hip/hip_runtime.h>
#include <cstdint>

#define BATCH 512
#define CIN   64
#define HH    32
#define WW    64
#define HW    2048
#define C1    32
#define C2    16
#define C3    8
#define C4    4
#define NOUT  256
#define KFC   8192
#define NODES 128
#define KS    32                      // FC K-split
#define GF_SIZE (BATCH * NODES * CIN)

typedef __attribute__((ext_vector_type(8))) short bfrag;   // 8 bf16 (4 VGPRs)
typedef __attribute__((ext_vector_type(4))) float ffrag;   // 4 fp32 acc

__device__ __forceinline__ ushort bf_trunc(float f) { return (ushort)(__float_as_uint(f) >> 16); }
__device__ __forceinline__ float  bf_truncf(float f) { return __uint_as_float(__float_as_uint(f) & 0xffff0000u); }
__device__ __forceinline__ ushort f2bf(float f) {
  uint32_t u = __float_as_uint(f);
  return (ushort)((u + 0x7fffu + ((u >> 16) & 1u)) >> 16);
}
__device__ __forceinline__ uint32_t pack2(float a, float b) {
  return (uint32_t)f2bf(a) | ((uint32_t)f2bf(b) << 16);
}
__device__ __forceinline__ uint32_t packhi2(float a, float b) {
  return (uint32_t)bf_trunc(a) | ((uint32_t)bf_trunc(b) << 16);
}

// ---------------------------------------------------------------------------
// K1: conv1 (1x1, 64->32) + conv2 (3x3 pad1, 32->16) fused, MFMA bf16,
// split-precision (fp32-grade).
// Round-2 proven structure (256 thr, 8-row tile, VGPR ~100, no spill) with
// the w2 LDS relay removed: W2 fragments are built from global AFTER the
// phase barrier (w12 is 18 KB, L2-resident; no Phase-A live-range growth).
// LDS = h1 only: [10][66][64B] = 42240 B -> 3 blocks/CU = 3 waves/SIMD.
// x NCHW fp32 -> h2 NHWC fp32 [cb][32][64][16].  grid (4, cb).
// ---------------------------------------------------------------------------
__global__ __launch_bounds__(256) void k_conv12(
    const float* __restrict__ x, const float* __restrict__ w11, const float* __restrict__ b11,
    const float* __restrict__ w12, const float* __restrict__ b12,
    float* __restrict__ h2, int b0)
{
  __shared__ __align__(16) char h1s[10 * 66 * 64];   // 42240 B
  const int tid = threadIdx.x;
  const int l   = tid & 63;
  const int wv  = tid >> 6;    // 0..3
  const int lr  = l & 15;
  const int lg  = l >> 4;
  const int r0  = blockIdx.x * 8;
  const int bg  = b0 + blockIdx.y;
  const float* xb = x + (size_t)bg * CIN * HW;

  // zero the padded columns (colb = 0 and 65) of all 10 rows
  if (tid < 160) {
    int row = tid >> 4, half = (tid >> 3) & 1, q = tid & 7;
    int cell = row * 66 + (half ? 65 : 0);
    *(uint2*)(h1s + (cell << 6) + q * 8) = uint2{0u, 0u};
  }

  // W1 fragments from global
  bfrag w1h[2][2], w1l[2][2];   // [Mtile][kstep]
  #pragma unroll
  for (int m = 0; m < 2; ++m) {
    #pragma unroll
    for (int ks = 0; ks < 2; ++ks) {
      const float* wp = w11 + (m * 16 + lr) * 64 + ks * 32 + lg * 8;
      #pragma unroll
      for (int e = 0; e < 8; ++e) {
        float v = wp[e];
        w1h[m][ks][e] = (short)bf_trunc(v);
        w1l[m][ks][e] = (short)f2bf(v - bf_truncf(v));
      }
    }
  }
  float bias1[2][4];
  #pragma unroll
  for (int m = 0; m < 2; ++m) {
    #pragma unroll
    for (int r = 0; r < 4; ++r) bias1[m][r] = b11[m * 16 + lg * 4 + r];
  }

  // ---- Phase A: conv1 -> h1 LDS. 40 tiles (10 rows x 4 col-tiles), 10/wave.
  #pragma unroll 2
  for (int i = 0; i < 10; ++i) {
    const int nt   = wv * 10 + i;
    const int ry   = nt >> 2;             // 0..9
    const int col0 = (nt & 3) << 4;
    const int y    = r0 - 1 + ry;
    const int colb = col0 + 1 + lr;
    if (y >= 0 && y < HH) {
      float xv[16];
      const float* xp = xb + y * WW + col0 + lr;
      #pragma unroll
      for (int ks = 0; ks < 2; ++ks) {
        #pragma unroll
        for (int e = 0; e < 8; ++e)
          xv[ks * 8 + e] = xp[(ks * 32 + lg * 8 + e) * HW];
      }
      bfrag xh[2], xl[2];
      #pragma unroll
      for (int ks = 0; ks < 2; ++ks) {
        #pragma unroll
        for (int e = 0; e < 8; ++e) {
          float v = xv[ks * 8 + e];
          xh[ks][e] = (short)bf_trunc(v);
          xl[ks][e] = (short)f2bf(v - bf_truncf(v));
        }
      }
      ffrag a0 = {0.f, 0.f, 0.f, 0.f}, a1 = {0.f, 0.f, 0.f, 0.f};
      #pragma unroll
      for (int ks = 0; ks < 2; ++ks) {
        a0 = __builtin_amdgcn_mfma_f32_16x16x32_bf16(w1h[0][ks], xh[ks], a0, 0, 0, 0);
        a0 = __builtin_amdgcn_mfma_f32_16x16x32_bf16(w1h[0][ks], xl[ks], a0, 0, 0, 0);
        a0 = __builtin_amdgcn_mfma_f32_16x16x32_bf16(w1l[0][ks], xh[ks], a0, 0, 0, 0);
        a1 = __builtin_amdgcn_mfma_f32_16x16x32_bf16(w1h[1][ks], xh[ks], a1, 0, 0, 0);
        a1 = __builtin_amdgcn_mfma_f32_16x16x32_bf16(w1h[1][ks], xl[ks], a1, 0, 0, 0);
        a1 = __builtin_amdgcn_mfma_f32_16x16x32_bf16(w1l[1][ks], xh[ks], a1, 0, 0, 0);
      }
      #pragma unroll
      for (int m = 0; m < 2; ++m) {
        float v0 = fmaxf((m ? a1[0] : a0[0]) + bias1[m][0], 0.f);
        float v1 = fmaxf((m ? a1[1] : a0[1]) + bias1[m][1], 0.f);
        float v2 = fmaxf((m ? a1[2] : a0[2]) + bias1[m][2], 0.f);
        float v3 = fmaxf((m ? a1[3] : a0[3]) + bias1[m][3], 0.f);
        int chunk = (m * 2 + (lg >> 1)) ^ ((colb >> 1) & 3);
        char* dst = h1s + ((ry * 66 + colb) << 6) + (chunk << 4) + (lg & 1) * 8;
        *(uint2*)dst = uint2{pack2(v0, v1), pack2(v2, v3)};
      }
    } else {
      #pragma unroll
      for (int m = 0; m < 2; ++m) {
        int chunk = (m * 2 + (lg >> 1)) ^ ((colb >> 1) & 3);
        char* dst = h1s + ((ry * 66 + colb) << 6) + (chunk << 4) + (lg & 1) * 8;
        *(uint2*)dst = uint2{0u, 0u};
      }
    }
  }
  __syncthreads();

  // W2 fragments from global, after the barrier (keeps Phase-A VGPR low).
  // w12 layout [o=16][c=32][tap=9]; lane lr = o, elems e -> c = lg*8+e.
  bfrag w2h[9], w2l[9];
  #pragma unroll
  for (int t = 0; t < 9; ++t) {
    const float* wp = w12 + lr * 288 + t;
    #pragma unroll
    for (int e = 0; e < 8; ++e) {
      float v = wp[(lg * 8 + e) * 9];
      w2h[t][e] = (short)bf_trunc(v);
      w2l[t][e] = (short)f2bf(v - bf_truncf(v));
    }
  }
  float bias2[4];
  #pragma unroll
  for (int r = 0; r < 4; ++r) bias2[r] = b12[lg * 4 + r];

  // ---- Phase B: conv2 (9 taps, K=32). 32 tiles (8 rows x 4), 8/wave.
  #pragma unroll 2
  for (int i = 0; i < 8; ++i) {
    const int nt   = wv * 8 + i;
    const int ryo  = nt >> 2;             // 0..7
    const int col0 = (nt & 3) << 4;
    ffrag acc = {0.f, 0.f, 0.f, 0.f};
    #pragma unroll
    for (int ky = 0; ky < 3; ++ky) {
      const int row = ryo + ky;
      #pragma unroll
      for (int kx = 0; kx < 3; ++kx) {
        const int colb  = col0 + lr + kx;
        const int chunk = lg ^ ((colb >> 1) & 3);
        const bfrag hv = *(const bfrag*)(h1s + ((row * 66 + colb) << 6) + (chunk << 4));
        acc = __builtin_amdgcn_mfma_f32_16x16x32_bf16(w2h[ky * 3 + kx], hv, acc, 0, 0, 0);
        acc = __builtin_amdgcn_mfma_f32_16x16x32_bf16(w2l[ky * 3 + kx], hv, acc, 0, 0, 0);
      }
    }
    const int px = (r0 + ryo) * WW + col0 + lr;
    float4 o;
    o.x = fmaxf(acc[0] + bias2[0], 0.f);
    o.y = fmaxf(acc[1] + bias2[1], 0.f);
    o.z = fmaxf(acc[2] + bias2[2], 0.f);
    o.w = fmaxf(acc[3] + bias2[3], 0.f);
    *(float4*)(h2 + ((size_t)blockIdx.y * HW + px) * 16 + lg * 4) = o;
  }
}

// ---------------------------------------------------------------------------
// K2: conv3 (1x1, 16->8, relu) + conv4 (3x3 pad1, 8->4, relu), fused (VALU).
// h2 NHWC fp32 -> h4 bf16 hi/lo planes [cb][8192] (FC flatten order).
// ---------------------------------------------------------------------------
__global__ __launch_bounds__(256) void k_conv34(
    const float* __restrict__ h2, const float* __restrict__ w21, const float* __restrict__ b21,
    const float* __restrict__ w22, const float* __restrict__ b22,
    ushort* __restrict__ h4h, ushort* __restrict__ h4l)
{
  __shared__ float h3s[18][64][9];
  __shared__ float __align__(16) w21s[128];
  __shared__ float __align__(16) w22s[288];
  const int tid = threadIdx.x;
  const int r0  = blockIdx.x * 16;
  const size_t b = blockIdx.y;

  for (int i = tid; i < 128; i += 256) w21s[(i & 15) * 8 + (i >> 4)] = w21[i];
  for (int i = tid; i < 288; i += 256) {
    int o = i / 72, r = i - o * 72, c = r / 9, tap = r - c * 9;
    w22s[(tap * 8 + c) * 4 + o] = w22[i];
  }
  __syncthreads();

  for (int p = tid; p < 18 * 64; p += 256) {
    const int ry = p >> 6, wc = p & 63;
    const int y  = r0 - 1 + ry;
    float* hd = &h3s[ry][wc][0];
    if (y >= 0 && y < HH) {
      const float4* hp = (const float4*)(h2 + ((b * HH + y) * WW + wc) * C2);
      float4 v0 = hp[0], v1 = hp[1], v2 = hp[2], v3 = hp[3];
      float xv[16] = {v0.x, v0.y, v0.z, v0.w, v1.x, v1.y, v1.z, v1.w,
                      v2.x, v2.y, v2.z, v2.w, v3.x, v3.y, v3.z, v3.w};
      float acc[C3];
      #pragma unroll
      for (int o = 0; o < C3; ++o) acc[o] = b21[o];
      #pragma unroll
      for (int c = 0; c < 16; ++c) {
        const float4* wr = (const float4*)&w21s[c * 8];
        float4 a = wr[0], d = wr[1];
        float v = xv[c];
        acc[0] = fmaf(v, a.x, acc[0]); acc[1] = fmaf(v, a.y, acc[1]);
        acc[2] = fmaf(v, a.z, acc[2]); acc[3] = fmaf(v, a.w, acc[3]);
        acc[4] = fmaf(v, d.x, acc[4]); acc[5] = fmaf(v, d.y, acc[5]);
        acc[6] = fmaf(v, d.z, acc[6]); acc[7] = fmaf(v, d.w, acc[7]);
      }
      #pragma unroll
      for (int c = 0; c < C3; ++c) hd[c] = fmaxf(acc[c], 0.f);
    } else {
      #pragma unroll
      for (int c = 0; c < C3; ++c) hd[c] = 0.f;
    }
  }
  __syncthreads();

  for (int p = tid; p < 1024; p += 256) {
    const int yl = p >> 6, wc = p & 63, ry = yl + 1;
    float acc[C4] = {b22[0], b22[1], b22[2], b22[3]};
    #pragma unroll
    for (int ky = 0; ky < 3; ++ky) {
      #pragma unroll
      for (int kx = 0; kx < 3; ++kx) {
        const int wcc = wc + kx - 1;
        if (wcc < 0 || wcc >= WW) continue;
        const float* hb = &h3s[ry + ky - 1][wcc][0];
        const int tap = ky * 3 + kx;
        #pragma unroll
        for (int c = 0; c < C3; ++c) {
          float v = hb[c];
          float4 w4 = *(const float4*)&w22s[(tap * 8 + c) * 4];
          acc[0] = fmaf(v, w4.x, acc[0]); acc[1] = fmaf(v, w4.y, acc[1]);
          acc[2] = fmaf(v, w4.z, acc[2]); acc[3] = fmaf(v, w4.w, acc[3]);
        }
      }
    }
    const size_t base = b * KFC + (r0 + yl) * WW + wc;
    #pragma unroll
    for (int o = 0; o < C4; ++o) {
      float v = fmaxf(acc[o], 0.f);
      h4h[base + (size_t)o * HW] = bf_trunc(v);
      h4l[base + (size_t)o * HW] = f2bf(v - bf_truncf(v));
    }
  }
}

// ---------------------------------------------------------------------------
// K2b: fcw fp32 -> bf16 hi/lo planes (once per launch, deterministic)
// ---------------------------------------------------------------------------
__global__ __launch_bounds__(256) void k_cvt_fcw(
    const float* __restrict__ w, ushort* __restrict__ hi, ushort* __restrict__ lo)
{
  const int i = (blockIdx.x * 256 + threadIdx.x) * 8;
  const float4 a = *(const float4*)(w + i);
  const float4 b = *(const float4*)(w + i + 4);
  uint4 hv, lv;
  hv.x = packhi2(a.x, a.y); hv.y = packhi2(a.z, a.w);
  hv.z = packhi2(b.x, b.y); hv.w = packhi2(b.z, b.w);
  lv.x = pack2(a.x - bf_truncf(a.x), a.y - bf_truncf(a.y));
  lv.y = pack2(a.z - bf_truncf(a.z), a.w - bf_truncf(a.w));
  lv.z = pack2(b.x - bf_truncf(b.x), b.y - bf_truncf(b.y));
  lv.w = pack2(b.z - bf_truncf(b.z), b.w - bf_truncf(b.w));
  *(uint4*)(hi + i) = hv;
  *(uint4*)(lo + i) = lv;
}

// ---------------------------------------------------------------------------
// K3: FC GEMM, MFMA bf16 3-product (hi/lo), K split KS-way, deterministic.
// ---------------------------------------------------------------------------
__global__ __launch_bounds__(256) void k_fc(
    const ushort* __restrict__ Ahp, const ushort* __restrict__ Alp,
    const ushort* __restrict__ Bhp, const ushort* __restrict__ Blp,
    float* __restrict__ zpart, int cb)
{
  const int tid = threadIdx.x;
  const int l   = tid & 63;
  const int wv  = tid >> 6;
  const int lr  = l & 15;
  const int lg  = l >> 4;
  const int m0  = blockIdx.x * 64 + (wv >> 1) * 32;
  const int n0  = blockIdx.y * 64 + (wv & 1) * 32;
  const int k0  = blockIdx.z * (KFC / KS);     // 256 per split

  int mrow[2], nrow[2];
  #pragma unroll
  for (int t = 0; t < 2; ++t) {
    int m = m0 + t * 16 + lr;
    mrow[t] = m < cb ? m : cb - 1;             // clamp; masked at write
    nrow[t] = n0 + t * 16 + lr;
  }
  ffrag acc[2][2] = {};

  #pragma unroll 1
  for (int kc = 0; kc < (KFC / KS) / 32; ++kc) {
    const int k = k0 + kc * 32 + lg * 8;
    bfrag ah[2], al[2], bh[2], bl[2];
    #pragma unroll
    for (int t = 0; t < 2; ++t) {
      ah[t] = *(const bfrag*)(Ahp + (size_t)mrow[t] * KFC + k);
      al[t] = *(const bfrag*)(Alp + (size_t)mrow[t] * KFC + k);
      bh[t] = *(const bfrag*)(Bhp + (size_t)nrow[t] * KFC + k);
      bl[t] = *(const bfrag*)(Blp + (size_t)nrow[t] * KFC + k);
    }
    #pragma unroll
    for (int mt = 0; mt < 2; ++mt) {
      #pragma unroll
      for (int nt = 0; nt < 2; ++nt) {
        acc[mt][nt] = __builtin_amdgcn_mfma_f32_16x16x32_bf16(ah[mt], bh[nt], acc[mt][nt], 0, 0, 0);
        acc[mt][nt] = __builtin_amdgcn_mfma_f32_16x16x32_bf16(ah[mt], bl[nt], acc[mt][nt], 0, 0, 0);
        acc[mt][nt] = __builtin_amdgcn_mfma_f32_16x16x32_bf16(al[mt], bh[nt], acc[mt][nt], 0, 0, 0);
      }
    }
  }

  #pragma unroll
  for (int mt = 0; mt < 2; ++mt) {
    #pragma unroll
    for (int r = 0; r < 4; ++r) {
      const int m = m0 + mt * 16 + lg * 4 + r;
      if (m < cb) {
        #pragma unroll
        for (int nt = 0; nt < 2; ++nt)
          zpart[((size_t)blockIdx.z * cb + m) * NOUT + n0 + nt * 16 + lr] = acc[mt][nt][r];
      }
    }
  }
}

// ---------------------------------------------------------------------------
// K4: reduce partials + bias -> sigmoid(3z) -> coord
// ---------------------------------------------------------------------------
__global__ __launch_bounds__(256) void k_coord(
    const float* __restrict__ zpart, const float* __restrict__ fcb,
    float* __restrict__ out, int cb, int b0)
{
  const int b = blockIdx.x;
  const int o = threadIdx.x;
  float z = fcb[o];
  #pragma unroll 8
  for (int kb = 0; kb < KS; ++kb) z += zpart[((size_t)kb * cb + b) * NOUT + o];
  float s = 1.f / (1.f + __expf(-3.f * z));
  const int node = o >> 1, comp = o & 1;
  out[GF_SIZE + (((size_t)(b0 + b) * NODES + node) << 1) + comp] = s * (comp ? 63.f : 31.f);
}

// ---------------------------------------------------------------------------
// K5: bilinear gather. One 64-lane group per (b,node); lane = channel.
// XCD-grouping swizzle (T1): all 32 blocks of one image share bid%8 so the
// image's 512 KB x-slab is fetched into ONE XCD's L2 instead of all eight.
// Guarded on cb%8==0 (bijective); falls back to identity otherwise.
// ---------------------------------------------------------------------------
__global__ __launch_bounds__(256) void k_gather(
    const float* __restrict__ x, float* __restrict__ out, int b0, int cb)
{
  const int bid = blockIdx.x;
  int bl, g;
  if ((cb & 7) == 0) {
    const int xcd = bid & 7;
    const int j   = bid >> 3;
    g  = j & 31;                 // 32 blocks per image
    bl = (j >> 5) * 8 + xcd;
  } else {
    bl = bid >> 5;
    g  = bid & 31;
  }
  const int node = g * 4 + (threadIdx.x >> 6);
  const int c    = threadIdx.x & 63;
  const int bg   = b0 + bl;
  const float* cp = out + GF_SIZE + ((size_t)bg * NODES + node) * 2;
  float chv = fminf(fmaxf(cp[0], 0.f), 31.f);
  float cwv = fminf(fmaxf(cp[1], 0.f), 63.f);
  float fh = floorf(chv), fw = floorf(cwv);
  int h0 = (int)fh, h1i = (int)ceilf(chv);
  int w0 = (int)fw, w1i = (int)ceilf(cwv);
  float oh = chv - fh, ow = cwv - fw;
  const float* xb = x + ((size_t)bg * CIN + c) * HW;
  float v_lt = xb[h0 * WW + w0];
  float v_rt = xb[h1i * WW + w0];
  float v_lb = xb[h0 * WW + w1i];
  float v_rb = xb[h1i * WW + w1i];
  float vt = v_lt + oh * (v_rt - v_lt);
  float vb = v_lb + oh * (v_rb - v_lb);
  out[((size_t)bg * NODES + node) * CIN + c] = vt + ow * (vb - vt);
}

// ---------------------------------------------------------------------------
extern "C" void kernel_launch(void* const* d_in, const int* in_sizes, int n_in,
                              void* d_out, int out_size, void* d_ws, size_t ws_size,
                              hipStream_t stream)
{
  (void)in_sizes; (void)n_in; (void)out_size;
  const float* x   = (const float*)d_in[0];
  const float* w11 = (const float*)d_in[1];
  const float* b11 = (const float*)d_in[2];
  const float* w12 = (const float*)d_in[3];
  const float* b12 = (const float*)d_in[4];
  const float* w21 = (const float*)d_in[5];
  const float* b21 = (const float*)d_in[6];
  const float* w22 = (const float*)d_in[7];
  const float* b22 = (const float*)d_in[8];
  const float* fcw = (const float*)d_in[9];
  const float* fcb = (const float*)d_in[10];
  float* out = (float*)d_out;
  char* wsb  = (char*)d_ws;

  // per-b: h2 fp32 (131072) + h4 hi/lo bf16 (2x16384) + zpart (KS*256*4)
  const size_t perB  = 131072 + 16384 + 16384 + (size_t)KS * NOUT * 4;
  const size_t fixed = 2 * 4194304;            // fcw hi/lo planes
  size_t avail = ws_size > fixed ? ws_size - fixed : perB;
  size_t cbmax = avail / perB;
  int CB = (int)(cbmax < (size_t)BATCH ? cbmax : (size_t)BATCH);
  if (CB < 1) CB = 1;

  char* p = wsb;
  float*  h2v  = (float*)p;   p += (size_t)CB * 131072;
  ushort* h4h  = (ushort*)p;  p += (size_t)CB * 16384;
  ushort* h4l  = (ushort*)p;  p += (size_t)CB * 16384;
  float*  zpv  = (float*)p;   p += (size_t)CB * KS * NOUT * 4;
  ushort* fcwh = (ushort*)p;  p += 4194304;
  ushort* fcwl = (ushort*)p;

  k_cvt_fcw<<<dim3(NOUT * KFC / (256 * 8)), 256, 0, stream>>>(fcw, fcwh, fcwl);

  for (int b0 = 0; b0 < BATCH; b0 += CB) {
    const int cb = (BATCH - b0 < CB) ? (BATCH - b0) : CB;
    k_conv12<<<dim3(4, cb), 256, 0, stream>>>(x, w11, b11, w12, b12, h2v, b0);
    k_conv34<<<dim3(2, cb), 256, 0, stream>>>(h2v, w21, b21, w22, b22, h4h, h4l);
    k_fc<<<dim3((cb + 63) / 64, 4, KS), 256, 0, stream>>>(h4h, h4l, fcwh, fcwl, zpv, cb);
    k_coord<<<dim3(cb), 256, 0, stream>>>(zpv, fcb, out, cb, b0);
    k_gather<<<dim3(cb * 32), 256, 0, stream>>>(x, out, b0, cb);
  }
}